// Round 11
// baseline (556.269 us; speedup 1.0000x reference)
//
#include <hip/hip_runtime.h>

#define EPS 1e-5f

typedef __attribute__((ext_vector_type(8))) short bf16x8;
typedef __attribute__((ext_vector_type(4))) float f32x4;

__device__ __forceinline__ unsigned short f2bf(float f) {
    unsigned u = __float_as_uint(f);
    u += 0x7fffu + ((u >> 16) & 1u);
    return (unsigned short)(u >> 16);
}
__device__ __forceinline__ float bf2f(unsigned short s) {
    return __uint_as_float(((unsigned)s) << 16);
}

// ---------------------------------------------------------------------------
__global__ void k_detect(const int* __restrict__ ei, int* __restrict__ flag) {
    if (blockIdx.x == 0 && threadIdx.x == 0) {
        int is64 = 1;
        for (int k = 0; k < 16; ++k) is64 &= (ei[2 * k + 1] == 0) ? 1 : 0;
        *flag = is64;
    }
}

// ---------------------------------------------------------------------------
// CSR build: histogram -> exclusive scan -> fill
__global__ void k_hist(const int* __restrict__ ei, const int* __restrict__ flag,
                       int E, int* __restrict__ cnt) {
    int e = blockIdx.x * blockDim.x + threadIdx.x;
    if (e >= E) return;
    int d = (*flag) ? (int)((const long long*)ei)[E + e] : ei[E + e];
    atomicAdd(&cnt[d], 1);
}

__device__ __forceinline__ int block_incl_scan(int v, int tid, int* total) {
    __shared__ int wsum[4];
    __shared__ int tot;
#pragma unroll
    for (int o = 1; o < 64; o <<= 1) {
        int u = __shfl_up(v, o, 64);
        if ((tid & 63) >= o) v += u;
    }
    if ((tid & 63) == 63) wsum[tid >> 6] = v;
    __syncthreads();
    int w = tid >> 6, add = 0;
    if (w > 0) add += wsum[0];
    if (w > 1) add += wsum[1];
    if (w > 2) add += wsum[2];
    v += add;
    if (tid == 255) tot = v;
    __syncthreads();
    *total = tot;
    __syncthreads();
    return v;
}

__global__ __launch_bounds__(256) void k_scanA(const int* __restrict__ cnt, int n,
                                               int* __restrict__ bsums) {
    int tid = threadIdx.x;
    int idx = blockIdx.x * 1024 + tid * 4;
    int s = 0;
#pragma unroll
    for (int k = 0; k < 4; ++k) { int i = idx + k; if (i < n) s += cnt[i]; }
#pragma unroll
    for (int o = 32; o > 0; o >>= 1) s += __shfl_xor(s, o, 64);
    __shared__ int ws[4];
    if ((tid & 63) == 0) ws[tid >> 6] = s;
    __syncthreads();
    if (tid == 0) bsums[blockIdx.x] = ws[0] + ws[1] + ws[2] + ws[3];
}

__global__ __launch_bounds__(256) void k_scanB(int* __restrict__ bsums, int nb,
                                               int* __restrict__ rowptr, int N) {
    int tid = threadIdx.x;
    __shared__ int sh_carry;
    if (tid == 0) sh_carry = 0;
    __syncthreads();
    int niter = (nb + 255) / 256;
    for (int it = 0; it < niter; ++it) {
        int i = it * 256 + tid;
        int v = (i < nb) ? bsums[i] : 0;
        int tot;
        int inc = block_incl_scan(v, tid, &tot);
        int carry = sh_carry;
        if (i < nb) bsums[i] = carry + inc - v;
        __syncthreads();
        if (tid == 0) sh_carry = carry + tot;
        __syncthreads();
    }
    if (tid == 0) rowptr[N] = sh_carry;
}

__global__ __launch_bounds__(256) void k_scanC(int* __restrict__ cnt_rowptr, int n,
                                               const int* __restrict__ bsums,
                                               int* __restrict__ cursor) {
    int tid = threadIdx.x;
    int idx = blockIdx.x * 1024 + tid * 4;
    int v[4]; int s = 0;
#pragma unroll
    for (int k = 0; k < 4; ++k) { int i = idx + k; v[k] = (i < n) ? cnt_rowptr[i] : 0; s += v[k]; }
    int tot;
    int inc = block_incl_scan(s, tid, &tot);
    int off = bsums[blockIdx.x] + inc - s;
#pragma unroll
    for (int k = 0; k < 4; ++k) {
        int i = idx + k;
        if (i < n) { cnt_rowptr[i] = off; cursor[i] = off; off += v[k]; }
    }
}

__global__ void k_fill(const int* __restrict__ ei, const int* __restrict__ flag, int E,
                       int* __restrict__ cursor, int* __restrict__ csr) {
    int e = blockIdx.x * blockDim.x + threadIdx.x;
    if (e >= E) return;
    int s, d;
    if (*flag) {
        s = (int)((const long long*)ei)[e];
        d = (int)((const long long*)ei)[E + e];
    } else {
        s = ei[e]; d = ei[E + e];
    }
    int pos = atomicAdd(&cursor[d], 1);
    csr[pos] = s;
}

// ---------------------------------------------------------------------------
// Degree sort: bucket = min(deg,63). LDS-aggregated histogram + fill.
__global__ __launch_bounds__(256) void k_dhist(const int* __restrict__ rowptr, int n,
                                               int* __restrict__ dcnt) {
    __shared__ int lh[64];
    int tid = threadIdx.x;
    if (tid < 64) lh[tid] = 0;
    __syncthreads();
    int i = blockIdx.x * 256 + tid;
    if (i < n) {
        int d = min(rowptr[i + 1] - rowptr[i], 63);
        atomicAdd(&lh[d], 1);
    }
    __syncthreads();
    if (tid < 64 && lh[tid] > 0) atomicAdd(&dcnt[tid], lh[tid]);
}

__global__ void k_dscan(const int* __restrict__ dcnt, int* __restrict__ dcur) {
    int tid = threadIdx.x;  // 64 threads
    int v = dcnt[tid];
    int inc = v;
#pragma unroll
    for (int o = 1; o < 64; o <<= 1) {
        int u = __shfl_up(inc, o, 64);
        if (tid >= o) inc += u;
    }
    dcur[tid] = inc - v;  // exclusive offsets
}

__global__ __launch_bounds__(256) void k_dfill(const int* __restrict__ rowptr, int n,
                                               int* __restrict__ dcur,
                                               int* __restrict__ perm,
                                               int2* __restrict__ rows2) {
    __shared__ int lh[64], lbase[64];
    int tid = threadIdx.x;
    if (tid < 64) lh[tid] = 0;
    __syncthreads();
    int i = blockIdx.x * 256 + tid;
    int d = 0, rank = 0, r0 = 0, r1 = 0;
    if (i < n) {
        r0 = rowptr[i]; r1 = rowptr[i + 1];
        d = min(r1 - r0, 63);
        rank = atomicAdd(&lh[d], 1);
    }
    __syncthreads();
    if (tid < 64 && lh[tid] > 0) lbase[tid] = atomicAdd(&dcur[tid], lh[tid]);
    __syncthreads();
    if (i < n) {
        int pos = lbase[d] + rank;
        perm[pos] = i;
        rows2[pos] = make_int2(r0, r1);
    }
}

// ---------------------------------------------------------------------------
__global__ void k_gather1(const float* __restrict__ x, const int* __restrict__ rowptr,
                          const int* __restrict__ csr, float* __restrict__ agg1, int n) {
    int i = blockIdx.x * blockDim.x + threadIdx.x;
    if (i >= n) return;
    int r0 = rowptr[i], r1 = rowptr[i + 1];
    float s0 = 0.f, s1 = 0.f;
    for (int j = r0; j < r1; ++j) {
        float2 v = ((const float2*)x)[csr[j]];
        s0 += v.x; s1 += v.y;
    }
    float inv = 1.f / fmaxf((float)(r1 - r0), 1.f);
    agg1[2 * i] = s0 * inv;
    agg1[2 * i + 1] = s1 * inv;
}

// ---------------------------------------------------------------------------
__global__ __launch_bounds__(256) void k_dense1(
    const float* __restrict__ x, const float* __restrict__ agg1,
    const float* __restrict__ W1l, const float* __restrict__ b1,
    const float* __restrict__ W1r,
    unsigned short* __restrict__ h1b, float* __restrict__ stats, int n) {
    int tid = threadIdx.x, c = tid & 63, w = tid >> 6;
    float wl0 = W1l[c], wl1 = W1l[64 + c];
    float wr0 = W1r[c], wr1 = W1r[64 + c];
    float bb = b1[c];
    float ls = 0.f, lq = 0.f;
    for (int i = blockIdx.x * 4 + w; i < n; i += gridDim.x * 4) {
        float a0 = agg1[2 * i], a1 = agg1[2 * i + 1];
        float x0 = x[2 * i], x1v = x[2 * i + 1];
        float h = fmaf(a0, wl0, fmaf(a1, wl1, fmaf(x0, wr0, fmaf(x1v, wr1, bb))));
        unsigned short hb = f2bf(h);
        h1b[(size_t)i * 64 + c] = hb;
        float hf = bf2f(hb);
        ls += hf; lq += hf * hf;
    }
    __shared__ float red[256];
    red[tid] = ls; __syncthreads();
    if (tid < 64) atomicAdd(&stats[tid], red[tid] + red[tid + 64] + red[tid + 128] + red[tid + 192]);
    __syncthreads();
    red[tid] = lq; __syncthreads();
    if (tid < 64) atomicAdd(&stats[64 + tid], red[tid] + red[tid + 64] + red[tid + 128] + red[tid + 192]);
}

// ---------------------------------------------------------------------------
__global__ void k_bnfin(const float* __restrict__ stats, const float* __restrict__ g,
                        const float* __restrict__ be, float* __restrict__ coef, float invN) {
    int c = threadIdx.x;
    float m = stats[c] * invN;
    float var = stats[64 + c] * invN - m * m;
    float a = g[c] * rsqrtf(var + EPS);
    coef[c] = a;
    coef[64 + c] = be[c] - m * a;
}

// ---------------------------------------------------------------------------
// Pre-transform (linear commute): x1 = relu(bn1(h1_i)); y_i = x1@W2l;
// z_i = x1@W2r + b2; PLUS layer-3 partials t1_i = x1.W3l, v1_i = x1.W3r
// via 2 extra MFMAs (B-frag cols: 0 = W3l, 1 = W3r).
#define LROW 72  // LDS row stride in shorts

__global__ __launch_bounds__(256) void k_dense_pre(
    const unsigned short* __restrict__ h1b, const float* __restrict__ coef1,
    const float* __restrict__ W2l, const float* __restrict__ b2,
    const float* __restrict__ W2r,
    const float* __restrict__ W3l, const float* __restrict__ W3r,
    unsigned short* __restrict__ y, unsigned short* __restrict__ z,
    float* __restrict__ t1, float* __restrict__ v1, int n) {
    __shared__ unsigned short lds_w[16 * 64 * 8];                 // 16 KB
    __shared__ __align__(16) unsigned short lds_y[4][16 * LROW];
    __shared__ __align__(16) unsigned short lds_z[4][16 * LROW];
    int tid = threadIdx.x, w = tid >> 6, l = tid & 63, ln = l & 15, kg = l >> 4;

    for (int idx = tid; idx < 4096; idx += 256) {
        int k = idx >> 6, c = idx & 63;
        int lane = ((k >> 3) & 3) * 16 + (c & 15);
        int fbase = ((k >> 5) * 4 + (c >> 4)) * 64 + lane;
        lds_w[fbase * 8 + (k & 7)] = f2bf(W2l[idx]);
        lds_w[(8 * 64 + fbase) * 8 + (k & 7)] = f2bf(W2r[idx]);
    }
    __syncthreads();

    float bb[4];
#pragma unroll
    for (int cs = 0; cs < 4; ++cs) bb[cs] = b2[cs * 16 + ln];
    float c1a[16], c1b[16];
#pragma unroll
    for (int j = 0; j < 8; ++j) {
        c1a[j]     = coef1[kg * 8 + j];       c1b[j]     = coef1[64 + kg * 8 + j];
        c1a[8 + j] = coef1[32 + kg * 8 + j];  c1b[8 + j] = coef1[96 + kg * 8 + j];
    }
    // W3 B-fragments: col 0 = W3l, col 1 = W3r, others 0
    bf16x8 b3a, b3b;
#pragma unroll
    for (int j = 0; j < 8; ++j) {
        float va = (ln == 0) ? W3l[kg * 8 + j] : ((ln == 1) ? W3r[kg * 8 + j] : 0.f);
        float vb = (ln == 0) ? W3l[32 + kg * 8 + j] : ((ln == 1) ? W3r[32 + kg * 8 + j] : 0.f);
        b3a[j] = (short)f2bf(va);
        b3b[j] = (short)f2bf(vb);
    }

    unsigned short* Ys = lds_y[w];
    unsigned short* Zs = lds_z[w];
    const bf16x8* wfrag = (const bf16x8*)lds_w;
    int nt = (n + 15) >> 4;
    int stride = gridDim.x * 4;

#define LOADH(T, A)                                                          \
    {                                                                        \
        int row_ = ((T) << 4) + ln;                                          \
        int rr_ = (row_ < n) ? row_ : (n - 1);                               \
        const unsigned short* xr_ = h1b + (size_t)rr_ * 64 + kg * 8;         \
        A##0 = *(const bf16x8*)xr_;                                          \
        A##1 = *(const bf16x8*)(xr_ + 32);                                   \
    }

#define PROCESSH(T, A)                                                       \
    {                                                                        \
        bf16x8 u0_, u1_;                                                     \
        _Pragma("unroll")                                                    \
        for (int j = 0; j < 8; ++j) {                                        \
            float f0_ = bf2f((unsigned short)A##0[j]);                       \
            float f1_ = bf2f((unsigned short)A##1[j]);                       \
            u0_[j] = (short)f2bf(fmaxf(0.f, fmaf(f0_, c1a[j], c1b[j])));     \
            u1_[j] = (short)f2bf(fmaxf(0.f, fmaf(f1_, c1a[8 + j], c1b[8 + j]))); \
        }                                                                    \
        f32x4 ya_[4], za_[4], a3_;                                           \
        _Pragma("unroll")                                                    \
        for (int cs = 0; cs < 4; ++cs) {                                     \
            ya_[cs] = (f32x4){0.f, 0.f, 0.f, 0.f};                           \
            za_[cs] = (f32x4){0.f, 0.f, 0.f, 0.f};                           \
        }                                                                    \
        a3_ = (f32x4){0.f, 0.f, 0.f, 0.f};                                   \
        _Pragma("unroll")                                                    \
        for (int cs = 0; cs < 4; ++cs) {                                     \
            ya_[cs] = __builtin_amdgcn_mfma_f32_16x16x32_bf16(u0_, wfrag[(0 * 4 + cs) * 64 + l], ya_[cs], 0, 0, 0);  \
            ya_[cs] = __builtin_amdgcn_mfma_f32_16x16x32_bf16(u1_, wfrag[(1 * 4 + cs) * 64 + l], ya_[cs], 0, 0, 0);  \
            za_[cs] = __builtin_amdgcn_mfma_f32_16x16x32_bf16(u0_, wfrag[(8 + cs) * 64 + l], za_[cs], 0, 0, 0);      \
            za_[cs] = __builtin_amdgcn_mfma_f32_16x16x32_bf16(u1_, wfrag[(12 + cs) * 64 + l], za_[cs], 0, 0, 0);     \
        }                                                                    \
        a3_ = __builtin_amdgcn_mfma_f32_16x16x32_bf16(u0_, b3a, a3_, 0, 0, 0); \
        a3_ = __builtin_amdgcn_mfma_f32_16x16x32_bf16(u1_, b3b, a3_, 0, 0, 0); \
        _Pragma("unroll")                                                    \
        for (int cs = 0; cs < 4; ++cs) {                                     \
            _Pragma("unroll")                                                \
            for (int r = 0; r < 4; ++r) {                                    \
                Ys[(kg * 4 + r) * LROW + cs * 16 + ln] = f2bf(ya_[cs][r]);   \
                Zs[(kg * 4 + r) * LROW + cs * 16 + ln] = f2bf(za_[cs][r] + bb[cs]); \
            }                                                                \
        }                                                                    \
        int base_ = (T) << 4;                                                \
        if (ln < 2) {                                                        \
            float* d3_ = (ln == 0) ? t1 : v1;                                \
            _Pragma("unroll")                                                \
            for (int r = 0; r < 4; ++r) {                                    \
                int row_ = base_ + kg * 4 + r;                               \
                if (row_ < n) d3_[row_] = a3_[r];                            \
            }                                                                \
        }                                                                    \
        asm volatile("s_waitcnt lgkmcnt(0)" ::: "memory");                   \
        int orow_ = l >> 2, oc_ = (l & 3) * 16;                              \
        if (base_ + orow_ < n) {                                             \
            const bf16x8* yp_ = (const bf16x8*)(Ys + orow_ * LROW + oc_);    \
            const bf16x8* zp_ = (const bf16x8*)(Zs + orow_ * LROW + oc_);    \
            bf16x8* yd_ = (bf16x8*)(y + (size_t)(base_ + orow_) * 64 + oc_); \
            bf16x8* zd_ = (bf16x8*)(z + (size_t)(base_ + orow_) * 64 + oc_); \
            yd_[0] = yp_[0]; yd_[1] = yp_[1];                                \
            zd_[0] = zp_[0]; zd_[1] = zp_[1];                                \
        }                                                                    \
        asm volatile("s_waitcnt lgkmcnt(0)" ::: "memory");                   \
    }

    bf16x8 P0, P1, Q0, Q1;
    int t = blockIdx.x * 4 + w;
    if (t < nt) {
        LOADH(t, P);
        while (t < nt) {
            int t1_ = t + stride;
            if (t1_ < nt) LOADH(t1_, Q);
            PROCESSH(t, P);
            int t2_ = t1_ + stride;
            if (t2_ < nt) LOADH(t2_, P);
            if (t1_ < nt) PROCESSH(t1_, Q);
            t = t2_;
        }
    }
#undef LOADH
#undef PROCESSH
}

// ---------------------------------------------------------------------------
// Gather + combine (degree-sorted): h2 = mean_j y[src_j] + z, in place on z.
// 8-lane groups; consecutive sorted positions -> equal degree in wave -> no
// divergence. rows2 gives coalesced row bounds. BN2 stats fused.
__global__ __launch_bounds__(256) void k_gather2b(
    const unsigned short* __restrict__ y, const int* __restrict__ perm,
    const int2* __restrict__ rows2,
    const int* __restrict__ csr, unsigned short* zh2,
    float* __restrict__ stats, int n) {
    int tid = threadIdx.x;
    int lg = tid & 7;
    int gid0 = blockIdx.x * 32 + (tid >> 3);
    int gstep = gridDim.x * 32;
    float ls[8] = {0.f, 0.f, 0.f, 0.f, 0.f, 0.f, 0.f, 0.f};
    float lq[8] = {0.f, 0.f, 0.f, 0.f, 0.f, 0.f, 0.f, 0.f};

    for (int gi = gid0; gi < n; gi += gstep) {
        int i = perm[gi];
        int2 rr = rows2[gi];
        int r0 = rr.x, r1 = rr.y;
        float s[8] = {0.f, 0.f, 0.f, 0.f, 0.f, 0.f, 0.f, 0.f};
        int j = r0;
        for (; j + 1 < r1; j += 2) {
            int a = csr[j], b = csr[j + 1];
            bf16x8 va = *(const bf16x8*)(y + (size_t)a * 64 + lg * 8);
            bf16x8 vb = *(const bf16x8*)(y + (size_t)b * 64 + lg * 8);
#pragma unroll
            for (int k = 0; k < 8; ++k)
                s[k] += bf2f((unsigned short)va[k]) + bf2f((unsigned short)vb[k]);
        }
        if (j < r1) {
            bf16x8 va = *(const bf16x8*)(y + (size_t)csr[j] * 64 + lg * 8);
#pragma unroll
            for (int k = 0; k < 8; ++k) s[k] += bf2f((unsigned short)va[k]);
        }
        float inv = 1.f / fmaxf((float)(r1 - r0), 1.f);
        bf16x8 z8 = *(const bf16x8*)(zh2 + (size_t)i * 64 + lg * 8);
        bf16x8 hb;
#pragma unroll
        for (int k = 0; k < 8; ++k) {
            float h = fmaf(s[k], inv, bf2f((unsigned short)z8[k]));
            unsigned short b = f2bf(h);
            hb[k] = (short)b;
            float hf = bf2f(b);
            ls[k] += hf; lq[k] += hf * hf;
        }
        *(bf16x8*)(zh2 + (size_t)i * 64 + lg * 8) = hb;
    }

#pragma unroll
    for (int k = 0; k < 8; ++k) {
        ls[k] += __shfl_xor(ls[k], 8, 64);
        ls[k] += __shfl_xor(ls[k], 16, 64);
        ls[k] += __shfl_xor(ls[k], 32, 64);
        lq[k] += __shfl_xor(lq[k], 8, 64);
        lq[k] += __shfl_xor(lq[k], 16, 64);
        lq[k] += __shfl_xor(lq[k], 32, 64);
    }
    __shared__ float red[2][4][64];
    int w = tid >> 6;
    if ((tid & 63) < 8) {
#pragma unroll
        for (int k = 0; k < 8; ++k) {
            red[0][w][lg * 8 + k] = ls[k];
            red[1][w][lg * 8 + k] = lq[k];
        }
    }
    __syncthreads();
    if (tid < 64) {
        atomicAdd(&stats[tid], red[0][0][tid] + red[0][1][tid] + red[0][2][tid] + red[0][3][tid]);
        atomicAdd(&stats[64 + tid], red[1][0][tid] + red[1][1][tid] + red[1][2][tid] + red[1][3][tid]);
    }
}

// ---------------------------------------------------------------------------
// Finalize: t = relu(bn2(h2)).W3l + t1;  v = relu(bn2(h2)).W3r + v1.
// Reads only zh2 (64MB) + t1/v1 (4MB) — h1b no longer needed here.
__global__ __launch_bounds__(256) void k_finalize(
    const unsigned short* __restrict__ h2b,
    const float* __restrict__ t1, const float* __restrict__ v1,
    const float* __restrict__ coef2,
    const float* __restrict__ W3l, const float* __restrict__ W3r,
    float* __restrict__ tb, float* __restrict__ vb, int n) {
    int tid = threadIdx.x, c = tid & 63, w = tid >> 6;
    int i0 = (blockIdx.x * 4 + w) * 8;
    if (i0 >= n) return;
    float a2 = coef2[c], b2 = coef2[64 + c];
    float wl = W3l[c], wr = W3r[c];
    float tv[8], vv[8];
#pragma unroll
    for (int q = 0; q < 8; ++q) {
        int i = i0 + q; int ic = (i < n) ? i : (n - 1);
        float h2v = bf2f(h2b[(size_t)ic * 64 + c]);
        float x2v = fmaxf(0.f, fmaf(h2v, a2, b2));
        tv[q] = x2v * wl; vv[q] = x2v * wr;
    }
#pragma unroll
    for (int q = 0; q < 8; ++q) {
        float t = tv[q], v = vv[q];
#pragma unroll
        for (int o = 32; o > 0; o >>= 1) {
            t += __shfl_xor(t, o, 64);
            v += __shfl_xor(v, o, 64);
        }
        int i = i0 + q;
        if (c == 0 && i < n) { tb[i] = t + t1[i]; vb[i] = v + v1[i]; }
    }
}

// ---------------------------------------------------------------------------
// Layer-3 gather (degree-sorted): out[i] = mean_j t[src_j] + v[i] + b3
__global__ void k_gather3(const float* __restrict__ tb, const float* __restrict__ vb,
                          const int* __restrict__ perm, const int2* __restrict__ rows2,
                          const int* __restrict__ csr,
                          const float* __restrict__ b3, float* __restrict__ out, int n) {
    int idx = blockIdx.x * blockDim.x + threadIdx.x;
    if (idx >= n) return;
    int i = perm[idx];
    int2 rr = rows2[idx];
    int r0 = rr.x, r1 = rr.y;
    float s = 0.f;
    int j = r0;
    for (; j + 3 < r1; j += 4)
        s += tb[csr[j]] + tb[csr[j + 1]] + tb[csr[j + 2]] + tb[csr[j + 3]];
    for (; j < r1; ++j) s += tb[csr[j]];
    float inv = 1.f / fmaxf((float)(r1 - r0), 1.f);
    out[i] = fmaf(s, inv, b3[0] + vb[i]);
}

// ---------------------------------------------------------------------------
// Workspace (4B units, N=500k, E=1.25M; cap 256 MiB = 67,108,864 units):
//   h1b 32N + y 32N + zh2 32N + R 2N + t1 N + v1 N + rowptr N+1 + csr E
//   + perm N + rows2 2N + bsums/stats/coef/flag/dcnt/dcur
//   = 104N + E + ~3k = 53.25M units = 213 MB (safe)
extern "C" void kernel_launch(void* const* d_in, const int* in_sizes, int n_in,
                              void* d_out, int out_size, void* d_ws, size_t ws_size,
                              hipStream_t stream) {
    const float* x   = (const float*)d_in[0];
    const int*   ei  = (const int*)d_in[1];
    const float* W1l = (const float*)d_in[2];
    const float* b1  = (const float*)d_in[3];
    const float* W1r = (const float*)d_in[4];
    const float* g1  = (const float*)d_in[5];
    const float* be1 = (const float*)d_in[6];
    const float* W2l = (const float*)d_in[7];
    const float* b2  = (const float*)d_in[8];
    const float* W2r = (const float*)d_in[9];
    const float* g2  = (const float*)d_in[10];
    const float* be2 = (const float*)d_in[11];
    const float* W3l = (const float*)d_in[12];
    const float* b3  = (const float*)d_in[13];
    const float* W3r = (const float*)d_in[14];

    int N = in_sizes[0] / 2;
    int E = in_sizes[1] / 2;

    float* ws   = (float*)d_ws;
    size_t nn   = (size_t)N;
    unsigned short* h1b = (unsigned short*)ws;             // 32N units
    unsigned short* y   = (unsigned short*)(ws + 32 * nn); // 32N units
    unsigned short* zh2 = (unsigned short*)(ws + 64 * nn); // 32N units (z -> h2)
    float* R     = ws + 96 * nn;            // 2N time-shared: cursor -> agg1 -> tb/vb
    int*   cursor = (int*)R;
    float* agg1   = R;
    float* tb     = R;
    float* vb     = R + nn;
    float* t1     = ws + 98 * nn;           // N
    float* v1     = ws + 99 * nn;           // N
    int*   rowptr = (int*)(ws + 100 * nn);  // N+1 (doubles as histogram cnt)
    int*   csr    = rowptr + (N + 1);       // E
    int*   perm   = csr + E;                // N
    int2*  rows2  = (int2*)(perm + N);      // N int2 = 2N units
    int*   bsums  = (int*)(rows2 + N);      // 2048
    float* stats  = (float*)(bsums + 2048); // 256: s1,q1 | s2,q2
    float* coef   = stats + 256;            // 256: a1,b1 | a2,b2
    int*   flag   = (int*)(coef + 256);     // 64
    int*   dcnt   = flag + 64;              // 64
    int*   dcur   = dcnt + 64;              // 64

    hipMemsetAsync(rowptr, 0, (size_t)(N + 1) * sizeof(int), stream);
    hipMemsetAsync(stats, 0, 256 * sizeof(float), stream);
    hipMemsetAsync(dcnt, 0, 64 * sizeof(int), stream);

    k_detect<<<1, 1, 0, stream>>>(ei, flag);

    int ge = (E + 255) / 256;
    int gn = (N + 255) / 256;
    int nb = (N + 1023) / 1024;
    k_hist<<<ge, 256, 0, stream>>>(ei, flag, E, rowptr);
    k_scanA<<<nb, 256, 0, stream>>>(rowptr, N, bsums);
    k_scanB<<<1, 256, 0, stream>>>(bsums, nb, rowptr, N);
    k_scanC<<<nb, 256, 0, stream>>>(rowptr, N, bsums, cursor);
    k_fill<<<ge, 256, 0, stream>>>(ei, flag, E, cursor, csr);
    // cursor dead; R becomes agg1

    k_dhist<<<gn, 256, 0, stream>>>(rowptr, N, dcnt);
    k_dscan<<<1, 64, 0, stream>>>(dcnt, dcur);
    k_dfill<<<gn, 256, 0, stream>>>(rowptr, N, dcur, perm, rows2);

    k_gather1<<<gn, 256, 0, stream>>>(x, rowptr, csr, agg1, N);
    k_dense1<<<1024, 256, 0, stream>>>(x, agg1, W1l, b1, W1r, h1b, stats, N);
    k_bnfin<<<1, 64, 0, stream>>>(stats, g1, be1, coef, 1.0f / (float)N);
    // agg1 dead after dense1

    k_dense_pre<<<2048, 256, 0, stream>>>(h1b, coef, W2l, b2, W2r, W3l, W3r,
                                          y, zh2, t1, v1, N);
    k_gather2b<<<2048, 256, 0, stream>>>(y, perm, rows2, csr, zh2, stats + 128, N);
    k_bnfin<<<1, 64, 0, stream>>>(stats + 128, g2, be2, coef + 128, 1.0f / (float)N);

    // R becomes tb/vb
    k_finalize<<<(N + 31) / 32, 256, 0, stream>>>(zh2, t1, v1, coef + 128,
                                                  W3l, W3r, tb, vb, N);
    k_gather3<<<gn, 256, 0, stream>>>(tb, vb, perm, rows2, csr, b3, (float*)d_out, N);
}

// Round 12
// 439.811 us; speedup vs baseline: 1.2648x; 1.2648x over previous
//
#include <hip/hip_runtime.h>

#define EPS 1e-5f

typedef __attribute__((ext_vector_type(8))) short bf16x8;
typedef __attribute__((ext_vector_type(4))) float f32x4;

__device__ __forceinline__ unsigned short f2bf(float f) {
    unsigned u = __float_as_uint(f);
    u += 0x7fffu + ((u >> 16) & 1u);
    return (unsigned short)(u >> 16);
}
__device__ __forceinline__ float bf2f(unsigned short s) {
    return __uint_as_float(((unsigned)s) << 16);
}

// ---------------------------------------------------------------------------
__global__ void k_detect(const int* __restrict__ ei, int* __restrict__ flag) {
    if (blockIdx.x == 0 && threadIdx.x == 0) {
        int is64 = 1;
        for (int k = 0; k < 16; ++k) is64 &= (ei[2 * k + 1] == 0) ? 1 : 0;
        *flag = is64;
    }
}

// ---------------------------------------------------------------------------
// CSR build: histogram -> exclusive scan -> fill
__global__ void k_hist(const int* __restrict__ ei, const int* __restrict__ flag,
                       int E, int* __restrict__ cnt) {
    int e = blockIdx.x * blockDim.x + threadIdx.x;
    if (e >= E) return;
    int d = (*flag) ? (int)((const long long*)ei)[E + e] : ei[E + e];
    atomicAdd(&cnt[d], 1);
}

__device__ __forceinline__ int block_incl_scan(int v, int tid, int* total) {
    __shared__ int wsum[4];
    __shared__ int tot;
#pragma unroll
    for (int o = 1; o < 64; o <<= 1) {
        int u = __shfl_up(v, o, 64);
        if ((tid & 63) >= o) v += u;
    }
    if ((tid & 63) == 63) wsum[tid >> 6] = v;
    __syncthreads();
    int w = tid >> 6, add = 0;
    if (w > 0) add += wsum[0];
    if (w > 1) add += wsum[1];
    if (w > 2) add += wsum[2];
    v += add;
    if (tid == 255) tot = v;
    __syncthreads();
    *total = tot;
    __syncthreads();
    return v;
}

__global__ __launch_bounds__(256) void k_scanA(const int* __restrict__ cnt, int n,
                                               int* __restrict__ bsums) {
    int tid = threadIdx.x;
    int idx = blockIdx.x * 1024 + tid * 4;
    int s = 0;
#pragma unroll
    for (int k = 0; k < 4; ++k) { int i = idx + k; if (i < n) s += cnt[i]; }
#pragma unroll
    for (int o = 32; o > 0; o >>= 1) s += __shfl_xor(s, o, 64);
    __shared__ int ws[4];
    if ((tid & 63) == 0) ws[tid >> 6] = s;
    __syncthreads();
    if (tid == 0) bsums[blockIdx.x] = ws[0] + ws[1] + ws[2] + ws[3];
}

__global__ __launch_bounds__(256) void k_scanB(int* __restrict__ bsums, int nb,
                                               int* __restrict__ rowptr, int N) {
    int tid = threadIdx.x;
    __shared__ int sh_carry;
    if (tid == 0) sh_carry = 0;
    __syncthreads();
    int niter = (nb + 255) / 256;
    for (int it = 0; it < niter; ++it) {
        int i = it * 256 + tid;
        int v = (i < nb) ? bsums[i] : 0;
        int tot;
        int inc = block_incl_scan(v, tid, &tot);
        int carry = sh_carry;
        if (i < nb) bsums[i] = carry + inc - v;
        __syncthreads();
        if (tid == 0) sh_carry = carry + tot;
        __syncthreads();
    }
    if (tid == 0) rowptr[N] = sh_carry;
}

__global__ __launch_bounds__(256) void k_scanC(int* __restrict__ cnt_rowptr, int n,
                                               const int* __restrict__ bsums,
                                               int* __restrict__ cursor) {
    int tid = threadIdx.x;
    int idx = blockIdx.x * 1024 + tid * 4;
    int v[4]; int s = 0;
#pragma unroll
    for (int k = 0; k < 4; ++k) { int i = idx + k; v[k] = (i < n) ? cnt_rowptr[i] : 0; s += v[k]; }
    int tot;
    int inc = block_incl_scan(s, tid, &tot);
    int off = bsums[blockIdx.x] + inc - s;
#pragma unroll
    for (int k = 0; k < 4; ++k) {
        int i = idx + k;
        if (i < n) { cnt_rowptr[i] = off; cursor[i] = off; off += v[k]; }
    }
}

__global__ void k_fill(const int* __restrict__ ei, const int* __restrict__ flag, int E,
                       int* __restrict__ cursor, int* __restrict__ csr) {
    int e = blockIdx.x * blockDim.x + threadIdx.x;
    if (e >= E) return;
    int s, d;
    if (*flag) {
        s = (int)((const long long*)ei)[e];
        d = (int)((const long long*)ei)[E + e];
    } else {
        s = ei[e]; d = ei[E + e];
    }
    int pos = atomicAdd(&cursor[d], 1);
    csr[pos] = s;
}

// ---------------------------------------------------------------------------
__global__ void k_gather1(const float* __restrict__ x, const int* __restrict__ rowptr,
                          const int* __restrict__ csr, float* __restrict__ agg1, int n) {
    int i = blockIdx.x * blockDim.x + threadIdx.x;
    if (i >= n) return;
    int r0 = rowptr[i], r1 = rowptr[i + 1];
    float s0 = 0.f, s1 = 0.f;
    for (int j = r0; j < r1; ++j) {
        float2 v = ((const float2*)x)[csr[j]];
        s0 += v.x; s1 += v.y;
    }
    float inv = 1.f / fmaxf((float)(r1 - r0), 1.f);
    agg1[2 * i] = s0 * inv;
    agg1[2 * i + 1] = s1 * inv;
}

// ---------------------------------------------------------------------------
// Second moments of u = (agg1_0, agg1_1, x_0, x_1): 4 first + 10 second = 14.
// BN1 stats are derived algebraically (h1 = u.W + b is linear) -> h1 is
// never materialized.
__global__ __launch_bounds__(256) void k_moments(
    const float* __restrict__ agg1, const float* __restrict__ xin,
    float* __restrict__ mom, int n) {
    int tid = threadIdx.x;
    float s[14];
#pragma unroll
    for (int k = 0; k < 14; ++k) s[k] = 0.f;
    for (int i = blockIdx.x * 256 + tid; i < n; i += gridDim.x * 256) {
        float2 a = ((const float2*)agg1)[i];
        float2 xv = ((const float2*)xin)[i];
        s[0] += a.x;  s[1] += a.y;  s[2] += xv.x; s[3] += xv.y;
        s[4] += a.x * a.x;   s[5] += a.x * a.y;   s[6] += a.x * xv.x;
        s[7] += a.x * xv.y;  s[8] += a.y * a.y;   s[9] += a.y * xv.x;
        s[10] += a.y * xv.y; s[11] += xv.x * xv.x; s[12] += xv.x * xv.y;
        s[13] += xv.y * xv.y;
    }
#pragma unroll
    for (int k = 0; k < 14; ++k) {
#pragma unroll
        for (int o = 32; o > 0; o >>= 1) s[k] += __shfl_xor(s[k], o, 64);
    }
    __shared__ float red[4][14];
    int w = tid >> 6;
    if ((tid & 63) == 0) {
#pragma unroll
        for (int k = 0; k < 14; ++k) red[w][k] = s[k];
    }
    __syncthreads();
    if (tid < 14)
        atomicAdd(&mom[tid], red[0][tid] + red[1][tid] + red[2][tid] + red[3][tid]);
}

// BN1-folded weights: x1_c = relu(a0*F0 + a1*F1 + x0*F2 + x1*F3 + F4).
// mean/var of h1_c from the quadratic form in the 5x5 moment matrix.
__global__ void k_bnfold1(const float* __restrict__ mom,
                          const float* __restrict__ W1l, const float* __restrict__ b1,
                          const float* __restrict__ W1r,
                          const float* __restrict__ g1, const float* __restrict__ be1,
                          float* __restrict__ fold, float invN) {
    int c = threadIdx.x;  // 64 threads
    float w0 = W1l[c], w1 = W1l[64 + c], w2 = W1r[c], w3 = W1r[64 + c], w4 = b1[c];
    float S0 = mom[0], S1 = mom[1], S2 = mom[2], S3 = mom[3];
    float lin = (S0 * w0 + S1 * w1 + S2 * w2 + S3 * w3) * invN;
    float mean = lin + w4;
    float q = mom[4] * w0 * w0 + mom[8] * w1 * w1 + mom[11] * w2 * w2 + mom[13] * w3 * w3
            + 2.f * (mom[5] * w0 * w1 + mom[6] * w0 * w2 + mom[7] * w0 * w3
                   + mom[9] * w1 * w2 + mom[10] * w1 * w3 + mom[12] * w2 * w3);
    float Eh2 = q * invN + 2.f * w4 * lin + w4 * w4;
    float var = Eh2 - mean * mean;
    float al = g1[c] * rsqrtf(var + EPS);
    float be = be1[c] - mean * al;
    fold[c]       = al * w0;
    fold[64 + c]  = al * w1;
    fold[128 + c] = al * w2;
    fold[192 + c] = al * w3;
    fold[256 + c] = al * w4 + be;
}

// ---------------------------------------------------------------------------
// BN2 finalize (stats -> affine coefs)
__global__ void k_bnfin(const float* __restrict__ stats, const float* __restrict__ g,
                        const float* __restrict__ be, float* __restrict__ coef, float invN) {
    int c = threadIdx.x;
    float m = stats[c] * invN;
    float var = stats[64 + c] * invN - m * m;
    float a = g[c] * rsqrtf(var + EPS);
    coef[c] = a;
    coef[64 + c] = be[c] - m * a;
}

// ---------------------------------------------------------------------------
// Pre-transform: x1 = relu(bn1-folded(agg1, x)) computed ON THE FLY (h1 never
// stored); y = x1@W2l; z = x1@W2r + b2; t1 = x1.W3l; v1 = x1.W3r (2 extra
// MFMAs). Outputs staged in wave-private LDS -> full-line stores.
#define LROW 72  // LDS row stride in shorts

__global__ __launch_bounds__(256) void k_dense_pre(
    const float* __restrict__ agg1, const float* __restrict__ xin,
    const float* __restrict__ fold,
    const float* __restrict__ W2l, const float* __restrict__ b2,
    const float* __restrict__ W2r,
    const float* __restrict__ W3l, const float* __restrict__ W3r,
    unsigned short* __restrict__ y, unsigned short* __restrict__ z,
    float* __restrict__ t1, float* __restrict__ v1, int n) {
    __shared__ unsigned short lds_w[16 * 64 * 8];                 // 16 KB
    __shared__ __align__(16) unsigned short lds_y[4][16 * LROW];
    __shared__ __align__(16) unsigned short lds_z[4][16 * LROW];
    int tid = threadIdx.x, w = tid >> 6, l = tid & 63, ln = l & 15, kg = l >> 4;

    for (int idx = tid; idx < 4096; idx += 256) {
        int k = idx >> 6, c = idx & 63;
        int lane = ((k >> 3) & 3) * 16 + (c & 15);
        int fbase = ((k >> 5) * 4 + (c >> 4)) * 64 + lane;
        lds_w[fbase * 8 + (k & 7)] = f2bf(W2l[idx]);
        lds_w[(8 * 64 + fbase) * 8 + (k & 7)] = f2bf(W2r[idx]);
    }
    __syncthreads();

    float bb[4];
#pragma unroll
    for (int cs = 0; cs < 4; ++cs) bb[cs] = b2[cs * 16 + ln];

    // BN1-folded weights for this lane's 16 channels (kg*8+j and 32+kg*8+j)
    float F0[16], F1[16], F2[16], F3[16], F4[16];
#pragma unroll
    for (int j = 0; j < 8; ++j) {
        int c = kg * 8 + j;
        F0[j] = fold[c];       F1[j] = fold[64 + c];  F2[j] = fold[128 + c];
        F3[j] = fold[192 + c]; F4[j] = fold[256 + c];
        c += 32;
        F0[8 + j] = fold[c];       F1[8 + j] = fold[64 + c];  F2[8 + j] = fold[128 + c];
        F3[8 + j] = fold[192 + c]; F4[8 + j] = fold[256 + c];
    }
    // W3 B-fragments: col 0 = W3l, col 1 = W3r, others 0
    bf16x8 b3a, b3b;
#pragma unroll
    for (int j = 0; j < 8; ++j) {
        float va = (ln == 0) ? W3l[kg * 8 + j] : ((ln == 1) ? W3r[kg * 8 + j] : 0.f);
        float vb = (ln == 0) ? W3l[32 + kg * 8 + j] : ((ln == 1) ? W3r[32 + kg * 8 + j] : 0.f);
        b3a[j] = (short)f2bf(va);
        b3b[j] = (short)f2bf(vb);
    }

    unsigned short* Ys = lds_y[w];
    unsigned short* Zs = lds_z[w];
    const bf16x8* wfrag = (const bf16x8*)lds_w;
    int nt = (n + 15) >> 4;
    int stride = gridDim.x * 4;

#define LOADH(T, A)                                                          \
    {                                                                        \
        int row_ = ((T) << 4) + ln;                                          \
        int rr_ = (row_ < n) ? row_ : (n - 1);                               \
        A##a = ((const float2*)agg1)[rr_];                                   \
        A##x = ((const float2*)xin)[rr_];                                    \
    }

#define PROCESSH(T, A)                                                       \
    {                                                                        \
        bf16x8 u0_, u1_;                                                     \
        _Pragma("unroll")                                                    \
        for (int j = 0; j < 8; ++j) {                                        \
            float h0_ = fmaf(A##a.x, F0[j], fmaf(A##a.y, F1[j],              \
                        fmaf(A##x.x, F2[j], fmaf(A##x.y, F3[j], F4[j]))));   \
            float h1_ = fmaf(A##a.x, F0[8 + j], fmaf(A##a.y, F1[8 + j],      \
                        fmaf(A##x.x, F2[8 + j], fmaf(A##x.y, F3[8 + j], F4[8 + j])))); \
            u0_[j] = (short)f2bf(fmaxf(0.f, h0_));                           \
            u1_[j] = (short)f2bf(fmaxf(0.f, h1_));                           \
        }                                                                    \
        f32x4 ya_[4], za_[4], a3_;                                           \
        _Pragma("unroll")                                                    \
        for (int cs = 0; cs < 4; ++cs) {                                     \
            ya_[cs] = (f32x4){0.f, 0.f, 0.f, 0.f};                           \
            za_[cs] = (f32x4){0.f, 0.f, 0.f, 0.f};                           \
        }                                                                    \
        a3_ = (f32x4){0.f, 0.f, 0.f, 0.f};                                   \
        _Pragma("unroll")                                                    \
        for (int cs = 0; cs < 4; ++cs) {                                     \
            ya_[cs] = __builtin_amdgcn_mfma_f32_16x16x32_bf16(u0_, wfrag[(0 * 4 + cs) * 64 + l], ya_[cs], 0, 0, 0);  \
            ya_[cs] = __builtin_amdgcn_mfma_f32_16x16x32_bf16(u1_, wfrag[(1 * 4 + cs) * 64 + l], ya_[cs], 0, 0, 0);  \
            za_[cs] = __builtin_amdgcn_mfma_f32_16x16x32_bf16(u0_, wfrag[(8 + cs) * 64 + l], za_[cs], 0, 0, 0);      \
            za_[cs] = __builtin_amdgcn_mfma_f32_16x16x32_bf16(u1_, wfrag[(12 + cs) * 64 + l], za_[cs], 0, 0, 0);     \
        }                                                                    \
        a3_ = __builtin_amdgcn_mfma_f32_16x16x32_bf16(u0_, b3a, a3_, 0, 0, 0); \
        a3_ = __builtin_amdgcn_mfma_f32_16x16x32_bf16(u1_, b3b, a3_, 0, 0, 0); \
        _Pragma("unroll")                                                    \
        for (int cs = 0; cs < 4; ++cs) {                                     \
            _Pragma("unroll")                                                \
            for (int r = 0; r < 4; ++r) {                                    \
                Ys[(kg * 4 + r) * LROW + cs * 16 + ln] = f2bf(ya_[cs][r]);   \
                Zs[(kg * 4 + r) * LROW + cs * 16 + ln] = f2bf(za_[cs][r] + bb[cs]); \
            }                                                                \
        }                                                                    \
        int base_ = (T) << 4;                                                \
        if (ln < 2) {                                                        \
            float* d3_ = (ln == 0) ? t1 : v1;                                \
            _Pragma("unroll")                                                \
            for (int r = 0; r < 4; ++r) {                                    \
                int row_ = base_ + kg * 4 + r;                               \
                if (row_ < n) d3_[row_] = a3_[r];                            \
            }                                                                \
        }                                                                    \
        asm volatile("s_waitcnt lgkmcnt(0)" ::: "memory");                   \
        int orow_ = l >> 2, oc_ = (l & 3) * 16;                              \
        if (base_ + orow_ < n) {                                             \
            const bf16x8* yp_ = (const bf16x8*)(Ys + orow_ * LROW + oc_);    \
            const bf16x8* zp_ = (const bf16x8*)(Zs + orow_ * LROW + oc_);    \
            bf16x8* yd_ = (bf16x8*)(y + (size_t)(base_ + orow_) * 64 + oc_); \
            bf16x8* zd_ = (bf16x8*)(z + (size_t)(base_ + orow_) * 64 + oc_); \
            yd_[0] = yp_[0]; yd_[1] = yp_[1];                                \
            zd_[0] = zp_[0]; zd_[1] = zp_[1];                                \
        }                                                                    \
        asm volatile("s_waitcnt lgkmcnt(0)" ::: "memory");                   \
    }

    float2 Pa, Px, Qa, Qx;
    int t = blockIdx.x * 4 + w;
    if (t < nt) {
        LOADH(t, P);
        while (t < nt) {
            int t1_ = t + stride;
            if (t1_ < nt) LOADH(t1_, Q);
            PROCESSH(t, P);
            int t2_ = t1_ + stride;
            if (t2_ < nt) LOADH(t2_, P);
            if (t1_ < nt) PROCESSH(t1_, Q);
            t = t2_;
        }
    }
#undef LOADH
#undef PROCESSH
}

// ---------------------------------------------------------------------------
// Gather + combine: h2_i = mean_j y[src_j] + z_i (z holds +b2), in place on z.
// 8-lane groups, 8 independent chains/wave; unsorted (coalesced z rows,
// streaming csr). BN2 stats fused.
__global__ __launch_bounds__(256) void k_gather2b(
    const unsigned short* __restrict__ y, const int* __restrict__ rowptr,
    const int* __restrict__ csr, unsigned short* zh2,
    float* __restrict__ stats, int n) {
    int tid = threadIdx.x;
    int lg = tid & 7;
    int gid0 = blockIdx.x * 32 + (tid >> 3);
    int gstep = gridDim.x * 32;
    float ls[8] = {0.f, 0.f, 0.f, 0.f, 0.f, 0.f, 0.f, 0.f};
    float lq[8] = {0.f, 0.f, 0.f, 0.f, 0.f, 0.f, 0.f, 0.f};

    for (int i = gid0; i < n; i += gstep) {
        int r0 = rowptr[i], r1 = rowptr[i + 1];
        float s[8] = {0.f, 0.f, 0.f, 0.f, 0.f, 0.f, 0.f, 0.f};
        int j = r0;
        for (; j + 1 < r1; j += 2) {
            int a = csr[j], b = csr[j + 1];
            bf16x8 va = *(const bf16x8*)(y + (size_t)a * 64 + lg * 8);
            bf16x8 vb = *(const bf16x8*)(y + (size_t)b * 64 + lg * 8);
#pragma unroll
            for (int k = 0; k < 8; ++k)
                s[k] += bf2f((unsigned short)va[k]) + bf2f((unsigned short)vb[k]);
        }
        if (j < r1) {
            bf16x8 va = *(const bf16x8*)(y + (size_t)csr[j] * 64 + lg * 8);
#pragma unroll
            for (int k = 0; k < 8; ++k) s[k] += bf2f((unsigned short)va[k]);
        }
        float inv = 1.f / fmaxf((float)(r1 - r0), 1.f);
        bf16x8 z8 = *(const bf16x8*)(zh2 + (size_t)i * 64 + lg * 8);
        bf16x8 hb;
#pragma unroll
        for (int k = 0; k < 8; ++k) {
            float h = fmaf(s[k], inv, bf2f((unsigned short)z8[k]));
            unsigned short b = f2bf(h);
            hb[k] = (short)b;
            float hf = bf2f(b);
            ls[k] += hf; lq[k] += hf * hf;
        }
        *(bf16x8*)(zh2 + (size_t)i * 64 + lg * 8) = hb;
    }

#pragma unroll
    for (int k = 0; k < 8; ++k) {
        ls[k] += __shfl_xor(ls[k], 8, 64);
        ls[k] += __shfl_xor(ls[k], 16, 64);
        ls[k] += __shfl_xor(ls[k], 32, 64);
        lq[k] += __shfl_xor(lq[k], 8, 64);
        lq[k] += __shfl_xor(lq[k], 16, 64);
        lq[k] += __shfl_xor(lq[k], 32, 64);
    }
    __shared__ float red[2][4][64];
    int w = tid >> 6;
    if ((tid & 63) < 8) {
#pragma unroll
        for (int k = 0; k < 8; ++k) {
            red[0][w][lg * 8 + k] = ls[k];
            red[1][w][lg * 8 + k] = lq[k];
        }
    }
    __syncthreads();
    if (tid < 64) {
        atomicAdd(&stats[tid], red[0][0][tid] + red[0][1][tid] + red[0][2][tid] + red[0][3][tid]);
        atomicAdd(&stats[64 + tid], red[1][0][tid] + red[1][1][tid] + red[1][2][tid] + red[1][3][tid]);
    }
}

// ---------------------------------------------------------------------------
// Finalize: t = relu(bn2(h2)).W3l + t1;  v = relu(bn2(h2)).W3r + v1.
__global__ __launch_bounds__(256) void k_finalize(
    const unsigned short* __restrict__ h2b,
    const float* __restrict__ t1, const float* __restrict__ v1,
    const float* __restrict__ coef2,
    const float* __restrict__ W3l, const float* __restrict__ W3r,
    float* __restrict__ tb, float* __restrict__ vb, int n) {
    int tid = threadIdx.x, c = tid & 63, w = tid >> 6;
    int i0 = (blockIdx.x * 4 + w) * 8;
    if (i0 >= n) return;
    float a2 = coef2[c], b2 = coef2[64 + c];
    float wl = W3l[c], wr = W3r[c];
    float tv[8], vv[8];
#pragma unroll
    for (int q = 0; q < 8; ++q) {
        int i = i0 + q; int ic = (i < n) ? i : (n - 1);
        float h2v = bf2f(h2b[(size_t)ic * 64 + c]);
        float x2v = fmaxf(0.f, fmaf(h2v, a2, b2));
        tv[q] = x2v * wl; vv[q] = x2v * wr;
    }
#pragma unroll
    for (int q = 0; q < 8; ++q) {
        float t = tv[q], v = vv[q];
#pragma unroll
        for (int o = 32; o > 0; o >>= 1) {
            t += __shfl_xor(t, o, 64);
            v += __shfl_xor(v, o, 64);
        }
        int i = i0 + q;
        if (c == 0 && i < n) { tb[i] = t + t1[i]; vb[i] = v + v1[i]; }
    }
}

// ---------------------------------------------------------------------------
// Layer-3 gather: out[i] = mean_j t[src_j] + v[i] + b3 (coalesced out writes)
__global__ void k_gather3(const float* __restrict__ tb, const float* __restrict__ vb,
                          const int* __restrict__ rowptr, const int* __restrict__ csr,
                          const float* __restrict__ b3, float* __restrict__ out, int n) {
    int i = blockIdx.x * blockDim.x + threadIdx.x;
    if (i >= n) return;
    int r0 = rowptr[i], r1 = rowptr[i + 1];
    float s = 0.f;
    int j = r0;
    for (; j + 3 < r1; j += 4)
        s += tb[csr[j]] + tb[csr[j + 1]] + tb[csr[j + 2]] + tb[csr[j + 3]];
    for (; j < r1; ++j) s += tb[csr[j]];
    float inv = 1.f / fmaxf((float)(r1 - r0), 1.f);
    out[i] = fmaf(s, inv, b3[0] + vb[i]);
}

// ---------------------------------------------------------------------------
// Workspace (4B units, N=500k, E=1.25M; cap 256 MiB = 67,108,864 units):
//   y 32N + zh2 32N + R 2N + t1 N + v1 N + rowptr N+1 + csr E + small
//   = 68N + E + ~1k = ~35.3M units = 141 MB (safe)
extern "C" void kernel_launch(void* const* d_in, const int* in_sizes, int n_in,
                              void* d_out, int out_size, void* d_ws, size_t ws_size,
                              hipStream_t stream) {
    const float* x   = (const float*)d_in[0];
    const int*   ei  = (const int*)d_in[1];
    const float* W1l = (const float*)d_in[2];
    const float* b1  = (const float*)d_in[3];
    const float* W1r = (const float*)d_in[4];
    const float* g1  = (const float*)d_in[5];
    const float* be1 = (const float*)d_in[6];
    const float* W2l = (const float*)d_in[7];
    const float* b2  = (const float*)d_in[8];
    const float* W2r = (const float*)d_in[9];
    const float* g2  = (const float*)d_in[10];
    const float* be2 = (const float*)d_in[11];
    const float* W3l = (const float*)d_in[12];
    const float* b3  = (const float*)d_in[13];
    const float* W3r = (const float*)d_in[14];

    int N = in_sizes[0] / 2;
    int E = in_sizes[1] / 2;

    float* ws   = (float*)d_ws;
    size_t nn   = (size_t)N;
    unsigned short* y   = (unsigned short*)ws;             // 32N units
    unsigned short* zh2 = (unsigned short*)(ws + 32 * nn); // 32N units (z -> h2)
    float* R     = ws + 64 * nn;            // 2N time-shared: cursor -> agg1 -> tb/vb
    int*   cursor = (int*)R;
    float* agg1   = R;
    float* tb     = R;
    float* vb     = R + nn;
    float* t1     = ws + 66 * nn;           // N
    float* v1     = ws + 67 * nn;           // N
    int*   rowptr = (int*)(ws + 68 * nn);   // N+1 (doubles as histogram cnt)
    int*   csr    = rowptr + (N + 1);       // E
    int*   bsums  = csr + E;                // 2048
    float* mom    = (float*)(bsums + 2048); // 16 (14 used)
    float* stats2 = mom + 16;               // 128: s2, q2
    float* coef2  = stats2 + 128;           // 128: a2, b2
    float* fold   = coef2 + 128;            // 320: F0..F4
    int*   flag   = (int*)(fold + 320);     // 64

    hipMemsetAsync(rowptr, 0, (size_t)(N + 1) * sizeof(int), stream);
    hipMemsetAsync(mom, 0, 16 * sizeof(float), stream);
    hipMemsetAsync(stats2, 0, 128 * sizeof(float), stream);

    k_detect<<<1, 1, 0, stream>>>(ei, flag);

    int ge = (E + 255) / 256;
    int gn = (N + 255) / 256;
    int nb = (N + 1023) / 1024;
    k_hist<<<ge, 256, 0, stream>>>(ei, flag, E, rowptr);
    k_scanA<<<nb, 256, 0, stream>>>(rowptr, N, bsums);
    k_scanB<<<1, 256, 0, stream>>>(bsums, nb, rowptr, N);
    k_scanC<<<nb, 256, 0, stream>>>(rowptr, N, bsums, cursor);
    k_fill<<<ge, 256, 0, stream>>>(ei, flag, E, cursor, csr);
    // cursor dead; R becomes agg1

    k_gather1<<<gn, 256, 0, stream>>>(x, rowptr, csr, agg1, N);
    k_moments<<<512, 256, 0, stream>>>(agg1, x, mom, N);
    k_bnfold1<<<1, 64, 0, stream>>>(mom, W1l, b1, W1r, g1, be1, fold, 1.0f / (float)N);

    k_dense_pre<<<2048, 256, 0, stream>>>(agg1, x, fold, W2l, b2, W2r, W3l, W3r,
                                          y, zh2, t1, v1, N);
    // agg1 dead after dense_pre

    k_gather2b<<<2048, 256, 0, stream>>>(y, rowptr, csr, zh2, stats2, N);
    k_bnfin<<<1, 64, 0, stream>>>(stats2, g2, be2, coef2, 1.0f / (float)N);

    // R becomes tb/vb
    k_finalize<<<(N + 31) / 32, 256, 0, stream>>>(zh2, t1, v1, coef2,
                                                  W3l, W3r, tb, vb, N);
    k_gather3<<<gn, 256, 0, stream>>>(tb, vb, rowptr, csr, b3, (float*)d_out, N);
}